// Round 6
// baseline (251.139 us; speedup 1.0000x reference)
//
#include <hip/hip_runtime.h>

// B=2, T=2048, C=1024, H=16, HD=64, ALPHA=32
// softmax((att - globalmax)*ALPHA) == softmax(att*ALPHA): the global-max shift
// cancels (softmax shift-invariant; -inf mask applied after the shift).
// Net: causal SDPA with scale 1/sqrt(HD)=0.125, all matmuls in bf16 MFMA.
// Q pre-scaled by 0.125*log2(e) in the QKV epilogue; softmax UN-SHIFTED in
// exp2 domain (order-independent sums -> KV tiles may be visited in ANY
// order); row-sum l via MFMA with ones.
//
// R1: QKV on 256x256/BK=64 counted-vmcnt schedule. R2: complementary map +
// tri-buffer (60.7). R3: regressed (confound). R4: double-buffer (54.4).
// R5: out-proj 128x64 2/CU (KEPT, ~-14us); attn ntile/2 rotation REGRESSED
// (FETCH 47->64MB: L2 stream scatter; 72.9us).
// R6: attn heavy-first equal-cost mapping (xr=15-x; co-res candidates at
// id-dist 1/16/256 equal or +-1 rank) + ONE-TILE stagger s0 in {0,1}
// (parity x^bh^(bh>>4)): de-phases the pair's barriers/MFMA bursts by a
// full iteration while K/V streams stay 1 tile apart (L2-adjacent).
// Evidence: lockstep-equal ~4750cyc/unit (R0), solo ~4200 (R2/R4 tails),
// overlapped-offset ~2600 (R4 overlap segments). Also fused cast+wtrans
// into one launch (prep_bf16).

#define Bsz 2
#define Tsz 2048
#define Csz 1024
#define Hsz 16
#define HDsz 64

typedef __bf16 bf16;
typedef __bf16 bf16x8 __attribute__((ext_vector_type(8)));
typedef __bf16 bf16x4 __attribute__((ext_vector_type(4)));
typedef float float4v __attribute__((ext_vector_type(4)));

#define MFMA16(a, b, c) __builtin_amdgcn_mfma_f32_16x16x32_bf16(a, b, c, 0, 0, 0)

// async global->LDS, 16B per lane; LDS dest must be lane-linear within a wave
#define GLOAD_LDS16(gptr, lptr)                                      \
  __builtin_amdgcn_global_load_lds(                                  \
      (const __attribute__((address_space(1))) void*)(gptr),         \
      (__attribute__((address_space(3))) void*)(lptr), 16, 0, 0)

// ---------------------------------------------------------------------------
// fused prep: blocks [0,6144): cast q/k/v f32->bf16 (8 elems/thread);
// blocks [6144,7168): transpose+cast Wq/Wk/Wv/Wp -> WT[N,K] bf16.
// ---------------------------------------------------------------------------
__global__ __launch_bounds__(256) void prep_bf16(
    const float* __restrict__ q, const float* __restrict__ k,
    const float* __restrict__ v, bf16* __restrict__ oq,
    bf16* __restrict__ ok, bf16* __restrict__ ov,
    const float* __restrict__ Wq, const float* __restrict__ Wk,
    const float* __restrict__ Wv, const float* __restrict__ Wp,
    bf16* __restrict__ WT) {
  __shared__ float Ts[64][68];
  const int bid = (int)blockIdx.x;
  const int tid = threadIdx.x;
  if (bid < 6144) {
    const int z = bid >> 11;  // /2048
    const int xb = bid & 2047;
    const float* src = z == 0 ? q : (z == 1 ? k : v);
    bf16* dst = z == 0 ? oq : (z == 1 ? ok : ov);
    const size_t i = ((size_t)xb * 256 + tid) * 8;
    const float4 a = *(const float4*)(src + i);
    const float4 b = *(const float4*)(src + i + 4);
    bf16x8 o;
    o[0] = (bf16)a.x; o[1] = (bf16)a.y; o[2] = (bf16)a.z; o[3] = (bf16)a.w;
    o[4] = (bf16)b.x; o[5] = (bf16)b.y; o[6] = (bf16)b.z; o[7] = (bf16)b.w;
    *(bf16x8*)(dst + i) = o;
  } else {
    const int w = bid - 6144;           // 0..1023
    const int z = w >> 8;               // weight select
    const int rem = w & 255;
    const int k0 = (rem >> 4) * 64, n0 = (rem & 15) * 64;
    const float* W = z == 0 ? Wq : (z == 1 ? Wk : (z == 2 ? Wv : Wp));
    bf16* out = WT + (size_t)z * (Csz * Csz);
#pragma unroll
    for (int it = 0; it < 4; ++it) {
      const int idx = it * 256 + tid;
      const int r = idx >> 4, c4 = (idx & 15) * 4;
      *(float4*)&Ts[r][c4] =
          *(const float4*)(W + (size_t)(k0 + r) * Csz + n0 + c4);
    }
    __syncthreads();
#pragma unroll
    for (int it = 0; it < 2; ++it) {
      const int idx = it * 256 + tid;
      const int n = idx & 63, k8 = (idx >> 6) * 8;
      bf16x8 o;
#pragma unroll
      for (int j = 0; j < 8; ++j) o[j] = (bf16)Ts[k8 + j][n];
      *(bf16x8*)(out + (size_t)(n0 + n) * Csz + k0 + k8) = o;
    }
  }
}

// ---------------------------------------------------------------------------
// QKV projection: 256x256 tile, BK=64, 512 thr = 8 waves (2Mx4N), 8-phase
// counted-vmcnt schedule (unchanged; verified round 1).
// ---------------------------------------------------------------------------
__global__ __launch_bounds__(512, 2) void gemm256_qkv(
    const bf16* __restrict__ A0, const bf16* __restrict__ A1,
    const bf16* __restrict__ A2, const bf16* __restrict__ Wt,
    const float* __restrict__ b0, const float* __restrict__ b1,
    const float* __restrict__ b2, bf16* __restrict__ C0,
    bf16* __restrict__ C1, bf16* __restrict__ Vt) {
  constexpr int NT = Csz / 64;  // 16 K-tiles
  const int z = blockIdx.z;
  const bf16* A = z == 0 ? A0 : (z == 1 ? A1 : A2);
  const float* bias = z == 0 ? b0 : (z == 1 ? b1 : b2);
  const bf16* Bt = Wt + (size_t)z * (Csz * Csz);
  const int m0 = blockIdx.y * 256;
  const int nz0 = blockIdx.x * 256;

  __shared__ bf16 As[2 * 256 * 64];
  __shared__ bf16 Bs[2 * 256 * 64];

  const int tid = threadIdx.x;
  const int wave = tid >> 6, lane = tid & 63;
  const int l15 = lane & 15, quad = lane >> 4;
  const int wm = wave >> 2, wn = wave & 3;

  const int srow = tid >> 3;  // 0..63
  const int sch = tid & 7;
  const bf16* Ab = A + (size_t)(m0 + srow) * Csz + (sch ^ (srow & 7)) * 8;
  const bf16* Bb = Bt + (size_t)(nz0 + srow) * Csz + (sch ^ (srow & 7)) * 8;

#define STG(Xb, lds, lbuf, hh, tt)                                           \
  {                                                                          \
    GLOAD_LDS16((Xb) + (size_t)((hh)*128) * Csz + (size_t)(tt)*64,           \
                &(lds)[(lbuf) * (256 * 64) + (hh)*8192 + tid * 8]);          \
    GLOAD_LDS16((Xb) + (size_t)((hh)*128 + 64) * Csz + (size_t)(tt)*64,     \
                &(lds)[(lbuf) * (256 * 64) + (hh)*8192 + 4096 + tid * 8]);  \
  }
#define RD_A(dst, lbuf, i2, ks)                                              \
  dst = *(const bf16x8*)&As[(lbuf) * (256 * 64) +                            \
                            (wm * 128 + (i2)*16 + l15) * 64 +                \
                            ((((ks)*4 + quad) ^ (l15 & 7)) * 8)];
#define RD_B(dst, lbuf, j2, ks)                                              \
  dst = *(const bf16x8*)&Bs[(lbuf) * (256 * 64) +                            \
                            (wn * 64 + (j2)*16 + l15) * 64 +                 \
                            ((((ks)*4 + quad) ^ (l15 & 7)) * 8)];

  float4v acc[8][4];
#pragma unroll
  for (int i = 0; i < 8; ++i)
#pragma unroll
    for (int j = 0; j < 4; ++j) acc[i][j] = (float4v){0.f, 0.f, 0.f, 0.f};

  // prologue: tile0 all 4 halves, tile1 A-halves (12 loads/thread total)
  STG(Ab, As, 0, 0, 0);
  STG(Ab, As, 0, 1, 0);
  STG(Bb, Bs, 0, 0, 0);
  STG(Bb, Bs, 0, 1, 0);
  STG(Ab, As, 1, 0, 1);
  STG(Ab, As, 1, 1, 1);
  asm volatile("s_waitcnt vmcnt(4)" ::: "memory");
  __builtin_amdgcn_s_barrier();
  __builtin_amdgcn_sched_barrier(0);

#pragma unroll 1
  for (int t = 0; t < NT; ++t) {
    const int bsel = t & 1;
    bf16x8 af0[4][2], af1[4][2], bf0[2][2], bf1[2][2];

    // ---- P1: quadrant (0,0) --------------------------------------------
#pragma unroll
    for (int i = 0; i < 4; ++i) {
      RD_A(af0[i][0], bsel, i, 0);
      RD_A(af0[i][1], bsel, i, 1);
    }
#pragma unroll
    for (int j = 0; j < 2; ++j) {
      RD_B(bf0[j][0], bsel, j, 0);
      RD_B(bf0[j][1], bsel, j, 1);
    }
    if (t + 1 < NT) STG(Bb, Bs, bsel ^ 1, 0, t + 1);
    __builtin_amdgcn_s_barrier();
    asm volatile("s_waitcnt lgkmcnt(0)" ::: "memory");
    __builtin_amdgcn_sched_barrier(0);
    __builtin_amdgcn_s_setprio(1);
#pragma unroll
    for (int i = 0; i < 4; ++i)
#pragma unroll
      for (int j = 0; j < 2; ++j) {
        acc[i][j] = MFMA16(af0[i][0], bf0[j][0], acc[i][j]);
        acc[i][j] = MFMA16(af0[i][1], bf0[j][1], acc[i][j]);
      }
    __builtin_amdgcn_s_setprio(0);
    __builtin_amdgcn_s_barrier();

    // ---- P2: quadrant (1,0) --------------------------------------------
#pragma unroll
    for (int i = 0; i < 4; ++i) {
      RD_A(af1[i][0], bsel, 4 + i, 0);
      RD_A(af1[i][1], bsel, 4 + i, 1);
    }
    if (t + 1 < NT) STG(Bb, Bs, bsel ^ 1, 1, t + 1);
    __builtin_amdgcn_s_barrier();
    asm volatile("s_waitcnt lgkmcnt(0)" ::: "memory");
    __builtin_amdgcn_sched_barrier(0);
    __builtin_amdgcn_s_setprio(1);
#pragma unroll
    for (int i = 0; i < 4; ++i)
#pragma unroll
      for (int j = 0; j < 2; ++j) {
        acc[4 + i][j] = MFMA16(af1[i][0], bf0[j][0], acc[4 + i][j]);
        acc[4 + i][j] = MFMA16(af1[i][1], bf0[j][1], acc[4 + i][j]);
      }
    __builtin_amdgcn_s_setprio(0);
    __builtin_amdgcn_s_barrier();

    // ---- P3: quadrant (0,1) --------------------------------------------
#pragma unroll
    for (int j = 0; j < 2; ++j) {
      RD_B(bf1[j][0], bsel, 2 + j, 0);
      RD_B(bf1[j][1], bsel, 2 + j, 1);
    }
    if (t + 2 < NT) STG(Ab, As, bsel, 0, t + 2);
    __builtin_amdgcn_s_barrier();
    asm volatile("s_waitcnt lgkmcnt(0)" ::: "memory");
    __builtin_amdgcn_sched_barrier(0);
    __builtin_amdgcn_s_setprio(1);
#pragma unroll
    for (int i = 0; i < 4; ++i)
#pragma unroll
      for (int j = 0; j < 2; ++j) {
        acc[i][2 + j] = MFMA16(af0[i][0], bf1[j][0], acc[i][2 + j]);
        acc[i][2 + j] = MFMA16(af0[i][1], bf1[j][1], acc[i][2 + j]);
      }
    __builtin_amdgcn_s_setprio(0);
    __builtin_amdgcn_s_barrier();

    // ---- P4: quadrant (1,1) --------------------------------------------
    if (t + 2 < NT) STG(Ab, As, bsel, 1, t + 2);
    __builtin_amdgcn_s_barrier();
    __builtin_amdgcn_s_setprio(1);
#pragma unroll
    for (int i = 0; i < 4; ++i)
#pragma unroll
      for (int j = 0; j < 2; ++j) {
        acc[4 + i][2 + j] = MFMA16(af1[i][0], bf1[j][0], acc[4 + i][2 + j]);
        acc[4 + i][2 + j] = MFMA16(af1[i][1], bf1[j][1], acc[4 + i][2 + j]);
      }
    __builtin_amdgcn_s_setprio(0);
    if (t + 2 < NT) {
      asm volatile("s_waitcnt vmcnt(4)" ::: "memory");
    } else if (t + 1 < NT) {
      asm volatile("s_waitcnt vmcnt(0)" ::: "memory");
    }
    __builtin_amdgcn_s_barrier();
    __builtin_amdgcn_sched_barrier(0);
  }
#undef STG
#undef RD_A
#undef RD_B

  const int omb0 = m0 + wm * 128 + quad * 4;
  const int onb0 = nz0 + wn * 64 + l15;
  if (z == 2) {
#pragma unroll
    for (int j = 0; j < 4; ++j) {
      const int n = onb0 + j * 16;
      const float bj = bias[n];
#pragma unroll
      for (int i = 0; i < 8; ++i) {
        const int mrow = omb0 + i * 16;
        const int bb = mrow >> 11, tt = mrow & (Tsz - 1);
        union { bf16 h[4]; uint2 u; } pk;
#pragma unroll
        for (int r = 0; r < 4; ++r) pk.h[r] = (bf16)(acc[i][j][r] + bj);
        *(uint2*)(Vt + ((size_t)(bb * 1024 + n)) * Tsz + tt) = pk.u;
      }
    }
  } else {
    bf16* C = z == 0 ? C0 : C1;
    const float osc = z == 0 ? 0.180336880111124f : 1.0f;  // 0.125*log2(e)
#pragma unroll
    for (int j = 0; j < 4; ++j) {
      const float bj = bias[onb0 + j * 16];
#pragma unroll
      for (int i = 0; i < 8; ++i) {
#pragma unroll
        for (int r = 0; r < 4; ++r) {
          const float v = (acc[i][j][r] + bj) * osc;
          C[(size_t)(omb0 + i * 16 + r) * Csz + onb0 + j * 16] = (bf16)v;
        }
      }
    }
  }
}

// ---------------------------------------------------------------------------
// Output projection: C[M,N] f32 = A[M,K]bf16 @ Bt[N,K]^T + bias.
// 128x64 tile, grid (16,32) = 512 blocks = 2/CU (kept from round 5, ~-14us).
// ---------------------------------------------------------------------------
__global__ __launch_bounds__(256) void gemm_op(
    const bf16* __restrict__ A, const bf16* __restrict__ Bt,
    const float* __restrict__ bias, float* __restrict__ C) {
  __shared__ bf16 As[128 * 32];
  __shared__ bf16 Bs[64 * 32];
  const int tid = threadIdx.x;
  const int wave = tid >> 6, lane = tid & 63;
  const int l15 = lane & 15, quad = lane >> 4;
  const int m0 = blockIdx.y * 128, n0 = blockIdx.x * 64;
  const int wm = (wave >> 1) * 64, wn = (wave & 1) * 32;
  const int srow = tid >> 2, schunk = tid & 3;

  float4v acc[4][2];
#pragma unroll
  for (int i = 0; i < 4; ++i)
#pragma unroll
    for (int j = 0; j < 2; ++j) acc[i][j] = (float4v){0.f, 0.f, 0.f, 0.f};

  for (int k0 = 0; k0 < Csz; k0 += 32) {
    __syncthreads();
#pragma unroll
    for (int p = 0; p < 2; ++p) {
      const int row = p * 64 + srow;
      GLOAD_LDS16(A + (size_t)(m0 + row) * Csz + k0 + schunk * 8,
                  &As[(p * 256 + tid) * 8]);
    }
    GLOAD_LDS16(Bt + (size_t)(n0 + srow) * Csz + k0 + schunk * 8,
                &Bs[tid * 8]);
    __syncthreads();

    bf16x8 af[4], bfr[2];
#pragma unroll
    for (int i = 0; i < 4; ++i)
      af[i] = *(const bf16x8*)&As[(wm + i * 16 + l15) * 32 + quad * 8];
#pragma unroll
    for (int j = 0; j < 2; ++j)
      bfr[j] = *(const bf16x8*)&Bs[(wn + j * 16 + l15) * 32 + quad * 8];
#pragma unroll
    for (int i = 0; i < 4; ++i)
#pragma unroll
      for (int j = 0; j < 2; ++j)
        acc[i][j] = MFMA16(af[i], bfr[j], acc[i][j]);
  }

  const int omb = m0 + wm + quad * 4;
  const int onb = n0 + wn + l15;
#pragma unroll
  for (int j = 0; j < 2; ++j) {
    const float bj = bias[onb + j * 16];
#pragma unroll
    for (int i = 0; i < 4; ++i) {
#pragma unroll
      for (int r = 0; r < 4; ++r)
        C[(size_t)(omb + i * 16 + r) * Csz + onb + j * 16] =
            acc[i][j][r] + bj;
    }
  }
}

// ---------------------------------------------------------------------------
// Flash attention, bf16 MFMA, S^T formulation. R4 double-buffered body.
// Round 6: heavy-first equal-cost mapping + ONE-tile stagger (de-phase
// co-resident equal pairs; K/V streams stay 1 tile apart -> L2-adjacent).
// ---------------------------------------------------------------------------
__global__ __launch_bounds__(256) void attn_mfma(const bf16* __restrict__ Q,
                                                 const bf16* __restrict__ K,
                                                 const bf16* __restrict__ Vt,
                                                 bf16* __restrict__ Y) {
  __shared__ bf16 Ks[2][64 * 64];
  __shared__ bf16 Vs[2][64 * 64];
  __shared__ bf16 Ps[4][32 * 72];  // per-wave P[q][key], row stride 72

  const int bh = blockIdx.y;
  const int b = bh >> 4, h = bh & 15;
  const int xr = (int)(gridDim.x - 1 - blockIdx.x);  // heavy-first, equal-cost
  const int i0 = xr * 128;
  const int tid = threadIdx.x;
  const int wave = tid >> 6, lane = tid & 63;
  const int l15 = lane & 15, quad = lane >> 4;

  const int srow = tid >> 3;  // 0..31
  const int sch = tid & 7;

  const bf16* kb = K + (size_t)b * Tsz * Csz + h * HDsz;
  const bf16* vb = Vt + (size_t)bh * HDsz * Tsz;

  const int qb = i0 + wave * 32;  // wave's first q row

  bf16x8 qf[2][2];
#pragma unroll
  for (int sub = 0; sub < 2; ++sub) {
    const bf16* qp =
        Q + ((size_t)(b * Tsz + qb + sub * 16 + l15)) * Csz + h * HDsz + quad * 8;
    qf[sub][0] = *(const bf16x8*)qp;
    qf[sub][1] = *(const bf16x8*)(qp + 32);
  }

  bf16x8 ones;
#pragma unroll
  for (int j = 0; j < 8; ++j) ones[j] = (bf16)1.0f;

  float4v Of[2][4];
  float4v accl[2];
#pragma unroll
  for (int sub = 0; sub < 2; ++sub) {
    accl[sub] = (float4v){0.f, 0.f, 0.f, 0.f};
#pragma unroll
    for (int nc = 0; nc < 4; ++nc) Of[sub][nc] = (float4v){0.f, 0.f, 0.f, 0.f};
  }

  const int ntile = i0 / 64 + 2;  // keys 0 .. i0+127 (>= 2 always)
  // ONE-tile stagger: parity differs across co-res candidates at id-dist
  // 1 (x), 16 (bh low), 256 (bh>>4). Order-free softmax makes this legal.
  const int s0 = ((int)blockIdx.x ^ bh ^ (bh >> 4)) & 1;

  // stage K/V tile tt into LDS buffer bb: 4 loads/thread (2 K + 2 V)
#define STAGE_KV(tt, bb)                                                     \
  {                                                                          \
    _Pragma("unroll") for (int p = 0; p < 2; ++p) {                          \
      const int r = p * 32 + srow;                                           \
      const int c = sch ^ (r & 7);                                           \
      GLOAD_LDS16(kb + (size_t)((tt)*64 + r) * Csz + c * 8,                  \
                  &Ks[bb][(p * 256 + tid) * 8]);                             \
      GLOAD_LDS16(vb + (size_t)r * Tsz + (tt)*64 + c * 8,                    \
                  &Vs[bb][(p * 256 + tid) * 8]);                             \
    }                                                                        \
  }

  // prologue: first (staggered) tile resident before first compute
  STAGE_KV(s0, 0);
  asm volatile("s_waitcnt vmcnt(0)" ::: "memory");
  __builtin_amdgcn_s_barrier();
  __builtin_amdgcn_sched_barrier(0);

#pragma unroll 1
  for (int s = 0; s < ntile; ++s) {
    int tp = s + s0;
    if (tp >= ntile) tp -= ntile;
    const int j0 = tp * 64;
    const int buf = s & 1;
    if (s + 1 < ntile) {
      int tn = tp + 1;
      if (tn >= ntile) tn -= ntile;
      STAGE_KV(tn, buf ^ 1);
    }

    if (j0 <= qb + 31) {  // wave-uniform: skip fully-masked tiles
      // ---- S^T = K Q^T : C-layout S^T[key=j0+nc*16+quad*4+r][q=qb+sub*16+l15]
      float4v S[2][4];
#pragma unroll
      for (int nc = 0; nc < 4; ++nc) {
        const int row = nc * 16 + l15;
        const bf16x8 k0 =
            *(const bf16x8*)&Ks[buf][row * 64 + ((quad ^ (row & 7)) * 8)];
        const bf16x8 k1 =
            *(const bf16x8*)&Ks[buf][row * 64 + (((quad + 4) ^ (row & 7)) * 8)];
#pragma unroll
        for (int sub = 0; sub < 2; ++sub) {
          float4v a = (float4v){0.f, 0.f, 0.f, 0.f};
          a = MFMA16(k0, qf[sub][0], a);
          a = MFMA16(k1, qf[sub][1], a);
          S[sub][nc] = a;
        }
      }

      // ---- causal mask: key > q  (wave-uniform branch, near-diagonal only)
      if (j0 + 63 > qb) {
#pragma unroll
        for (int sub = 0; sub < 2; ++sub) {
          const int q = qb + sub * 16 + l15;
#pragma unroll
          for (int nc = 0; nc < 4; ++nc) {
            const int keyb = j0 + nc * 16 + quad * 4;
#pragma unroll
            for (int r = 0; r < 4; ++r)
              if (keyb + r > q) S[sub][nc][r] = -1e30f;
          }
        }
      }

      // ---- un-shifted exp2 numerator; P[q][key] -> LDS (b64, r contiguous)
#pragma unroll
      for (int sub = 0; sub < 2; ++sub) {
#pragma unroll
        for (int nc = 0; nc < 4; ++nc) {
          bf16x4 pk;
#pragma unroll
          for (int r = 0; r < 4; ++r)
            pk[r] = (bf16)__builtin_amdgcn_exp2f(S[sub][nc][r]);
          *(bf16x4*)&Ps[wave][(sub * 16 + l15) * 72 + nc * 16 + quad * 4] = pk;
        }
      }

      // ---- P^T B-frags (b128), l, and O^T += V^T P^T (same-wave LDS RAW) --
      bf16x8 pf[2][2];
#pragma unroll
      for (int sub = 0; sub < 2; ++sub) {
#pragma unroll
        for (int kc = 0; kc < 2; ++kc)
          pf[sub][kc] = *(const bf16x8*)
              &Ps[wave][(sub * 16 + l15) * 72 + kc * 32 + quad * 8];
        accl[sub] = MFMA16(ones, pf[sub][0], accl[sub]);
        accl[sub] = MFMA16(ones, pf[sub][1], accl[sub]);
      }
#pragma unroll
      for (int nc = 0; nc < 4; ++nc) {
        const int row = nc * 16 + l15;
#pragma unroll
        for (int kc = 0; kc < 2; ++kc) {
          const bf16x8 vf = *(const bf16x8*)
              &Vs[buf][row * 64 + (((kc * 4 + quad) ^ (row & 7)) * 8)];
#pragma unroll
          for (int sub = 0; sub < 2; ++sub)
            Of[sub][nc] = MFMA16(vf, pf[sub][kc], Of[sub][nc]);
        }
      }
    }

    // ---- gate: next tile resident before next iter ----
    if (s + 1 < ntile) {
      asm volatile("s_waitcnt vmcnt(0)" ::: "memory");
    }
    __builtin_amdgcn_sched_barrier(0);
    __builtin_amdgcn_s_barrier();
    __builtin_amdgcn_sched_barrier(0);
  }
#undef STAGE_KV

  // ---- epilogue: Y[q][h*64+d] = O^T[d][q] / l[q]  (8B stores, r contiguous)
#pragma unroll
  for (int sub = 0; sub < 2; ++sub) {
    const float rl = __builtin_amdgcn_rcpf(accl[sub][0]);
    const size_t rowoff =
        ((size_t)(b * Tsz + qb + sub * 16 + l15)) * Csz + h * HDsz;
#pragma unroll
    for (int nc = 0; nc < 4; ++nc) {
      union { bf16 h4[4]; uint2 u; } pk;
#pragma unroll
      for (int r = 0; r < 4; ++r) pk.h4[r] = (bf16)(Of[sub][nc][r] * rl);
      *(uint2*)(Y + rowoff + nc * 16 + quad * 4) = pk.u;
    }
  }
}

extern "C" void kernel_launch(void* const* d_in, const int* in_sizes, int n_in,
                              void* d_out, int out_size, void* d_ws,
                              size_t ws_size, hipStream_t stream) {
  const float* query = (const float*)d_in[0];
  const float* key = (const float*)d_in[1];
  const float* value = (const float*)d_in[2];
  // d_in[3] = att_mask (tril causal) -- hard-coded in attn kernel
  const float* Wq = (const float*)d_in[4];
  const float* bq = (const float*)d_in[5];
  const float* Wk = (const float*)d_in[6];
  const float* bk = (const float*)d_in[7];
  const float* Wv = (const float*)d_in[8];
  const float* bv = (const float*)d_in[9];
  const float* Wp = (const float*)d_in[10];
  const float* bp = (const float*)d_in[11];
  float* out = (float*)d_out;

  char* ws = (char*)d_ws;
  bf16* WT = (bf16*)(ws);
  bf16* vc = (bf16*)(ws + (8u << 20));
  bf16* Qp = (bf16*)(ws + (16u << 20));
  bf16* Kp = (bf16*)(ws + (24u << 20));
  bf16* Vt = (bf16*)(ws + (32u << 20));
  bf16* Yb = vc;
  bf16* qc = (bf16*)d_out;
  bf16* kc = (bf16*)((char*)d_out + (8u << 20));

  const int M = Bsz * Tsz;  // 4096

  // fused cast(q,k,v) + weight transpose: 6144 + 1024 blocks
  prep_bf16<<<dim3(7168), dim3(256), 0, stream>>>(query, key, value, qc, kc,
                                                  vc, Wq, Wk, Wv, Wp, WT);
  // batched QKV projection, 256^2 8-phase; z==0 pre-scales Q; z==2 -> Vt
  gemm256_qkv<<<dim3(Csz / 256, M / 256, 3), dim3(512), 0, stream>>>(
      qc, kc, vc, WT, bq, bk, bv, Qp, Kp, Vt);
  // flash attention (writes bf16 into Yb = old vc slot)
  attn_mfma<<<dim3(Tsz / 128, Bsz * Hsz), dim3(256), 0, stream>>>(Qp, Kp, Vt,
                                                                  Yb);
  // output projection (f32 into d_out), 128x64 tiles, 512 blocks = 2/CU
  gemm_op<<<dim3(Csz / 64, M / 128), dim3(256), 0, stream>>>(
      Yb, WT + 3u * (Csz * Csz), bp, out);
}

// Round 7
// 226.725 us; speedup vs baseline: 1.1077x; 1.1077x over previous
//
#include <hip/hip_runtime.h>

// B=2, T=2048, C=1024, H=16, HD=64, ALPHA=32
// softmax((att - globalmax)*ALPHA) == softmax(att*ALPHA): the global-max shift
// cancels (softmax shift-invariant; -inf mask applied after the shift).
// Net: causal SDPA with scale 1/sqrt(HD)=0.125, all matmuls in bf16 MFMA.
// Q pre-scaled by 0.125*log2(e) in the QKV epilogue; softmax UN-SHIFTED in
// exp2 domain; row-sum l via MFMA with ones.
//
// R1: QKV on 256x256/BK=64 counted-vmcnt schedule. R2: complementary map +
// tri-buffer (60.7). R3/R5/R6: scheduling experiments all regressed vs
// R4 (54.4us, complementary map + double-buffer). R5 kept: out-proj 128x64
// 2/CU (~-14us). R6 kept: fused prep.
// Round 7: attn 8 waves x 16 q-rows per 128-row block (was 4 x 32). Same
// grid/LDS/mapping as R4; per-block-tile MFMA count unchanged (144) but
// 2 blk/CU x 8 waves = 4 waves/SIMD paired, 2 waves/SIMD even when a heavy
// block runs solo -> the 1-wave/SIMD latency-exposed regime (R4's ~3800
// cyc/unit vs ~2375 paired, R0 data) is structurally eliminated.

#define Bsz 2
#define Tsz 2048
#define Csz 1024
#define Hsz 16
#define HDsz 64

typedef __bf16 bf16;
typedef __bf16 bf16x8 __attribute__((ext_vector_type(8)));
typedef __bf16 bf16x4 __attribute__((ext_vector_type(4)));
typedef float float4v __attribute__((ext_vector_type(4)));

#define MFMA16(a, b, c) __builtin_amdgcn_mfma_f32_16x16x32_bf16(a, b, c, 0, 0, 0)

// async global->LDS, 16B per lane; LDS dest must be lane-linear within a wave
#define GLOAD_LDS16(gptr, lptr)                                      \
  __builtin_amdgcn_global_load_lds(                                  \
      (const __attribute__((address_space(1))) void*)(gptr),         \
      (__attribute__((address_space(3))) void*)(lptr), 16, 0, 0)

// ---------------------------------------------------------------------------
// fused prep: blocks [0,6144): cast q/k/v f32->bf16 (8 elems/thread);
// blocks [6144,7168): transpose+cast Wq/Wk/Wv/Wp -> WT[N,K] bf16.
// ---------------------------------------------------------------------------
__global__ __launch_bounds__(256) void prep_bf16(
    const float* __restrict__ q, const float* __restrict__ k,
    const float* __restrict__ v, bf16* __restrict__ oq,
    bf16* __restrict__ ok, bf16* __restrict__ ov,
    const float* __restrict__ Wq, const float* __restrict__ Wk,
    const float* __restrict__ Wv, const float* __restrict__ Wp,
    bf16* __restrict__ WT) {
  __shared__ float Ts[64][68];
  const int bid = (int)blockIdx.x;
  const int tid = threadIdx.x;
  if (bid < 6144) {
    const int z = bid >> 11;  // /2048
    const int xb = bid & 2047;
    const float* src = z == 0 ? q : (z == 1 ? k : v);
    bf16* dst = z == 0 ? oq : (z == 1 ? ok : ov);
    const size_t i = ((size_t)xb * 256 + tid) * 8;
    const float4 a = *(const float4*)(src + i);
    const float4 b = *(const float4*)(src + i + 4);
    bf16x8 o;
    o[0] = (bf16)a.x; o[1] = (bf16)a.y; o[2] = (bf16)a.z; o[3] = (bf16)a.w;
    o[4] = (bf16)b.x; o[5] = (bf16)b.y; o[6] = (bf16)b.z; o[7] = (bf16)b.w;
    *(bf16x8*)(dst + i) = o;
  } else {
    const int w = bid - 6144;           // 0..1023
    const int z = w >> 8;               // weight select
    const int rem = w & 255;
    const int k0 = (rem >> 4) * 64, n0 = (rem & 15) * 64;
    const float* W = z == 0 ? Wq : (z == 1 ? Wk : (z == 2 ? Wv : Wp));
    bf16* out = WT + (size_t)z * (Csz * Csz);
#pragma unroll
    for (int it = 0; it < 4; ++it) {
      const int idx = it * 256 + tid;
      const int r = idx >> 4, c4 = (idx & 15) * 4;
      *(float4*)&Ts[r][c4] =
          *(const float4*)(W + (size_t)(k0 + r) * Csz + n0 + c4);
    }
    __syncthreads();
#pragma unroll
    for (int it = 0; it < 2; ++it) {
      const int idx = it * 256 + tid;
      const int n = idx & 63, k8 = (idx >> 6) * 8;
      bf16x8 o;
#pragma unroll
      for (int j = 0; j < 8; ++j) o[j] = (bf16)Ts[k8 + j][n];
      *(bf16x8*)(out + (size_t)(n0 + n) * Csz + k0 + k8) = o;
    }
  }
}

// ---------------------------------------------------------------------------
// QKV projection: 256x256 tile, BK=64, 512 thr = 8 waves (2Mx4N), 8-phase
// counted-vmcnt schedule (unchanged; verified round 1).
// ---------------------------------------------------------------------------
__global__ __launch_bounds__(512, 2) void gemm256_qkv(
    const bf16* __restrict__ A0, const bf16* __restrict__ A1,
    const bf16* __restrict__ A2, const bf16* __restrict__ Wt,
    const float* __restrict__ b0, const float* __restrict__ b1,
    const float* __restrict__ b2, bf16* __restrict__ C0,
    bf16* __restrict__ C1, bf16* __restrict__ Vt) {
  constexpr int NT = Csz / 64;  // 16 K-tiles
  const int z = blockIdx.z;
  const bf16* A = z == 0 ? A0 : (z == 1 ? A1 : A2);
  const float* bias = z == 0 ? b0 : (z == 1 ? b1 : b2);
  const bf16* Bt = Wt + (size_t)z * (Csz * Csz);
  const int m0 = blockIdx.y * 256;
  const int nz0 = blockIdx.x * 256;

  __shared__ bf16 As[2 * 256 * 64];
  __shared__ bf16 Bs[2 * 256 * 64];

  const int tid = threadIdx.x;
  const int wave = tid >> 6, lane = tid & 63;
  const int l15 = lane & 15, quad = lane >> 4;
  const int wm = wave >> 2, wn = wave & 3;

  const int srow = tid >> 3;  // 0..63
  const int sch = tid & 7;
  const bf16* Ab = A + (size_t)(m0 + srow) * Csz + (sch ^ (srow & 7)) * 8;
  const bf16* Bb = Bt + (size_t)(nz0 + srow) * Csz + (sch ^ (srow & 7)) * 8;

#define STG(Xb, lds, lbuf, hh, tt)                                           \
  {                                                                          \
    GLOAD_LDS16((Xb) + (size_t)((hh)*128) * Csz + (size_t)(tt)*64,           \
                &(lds)[(lbuf) * (256 * 64) + (hh)*8192 + tid * 8]);          \
    GLOAD_LDS16((Xb) + (size_t)((hh)*128 + 64) * Csz + (size_t)(tt)*64,     \
                &(lds)[(lbuf) * (256 * 64) + (hh)*8192 + 4096 + tid * 8]);  \
  }
#define RD_A(dst, lbuf, i2, ks)                                              \
  dst = *(const bf16x8*)&As[(lbuf) * (256 * 64) +                            \
                            (wm * 128 + (i2)*16 + l15) * 64 +                \
                            ((((ks)*4 + quad) ^ (l15 & 7)) * 8)];
#define RD_B(dst, lbuf, j2, ks)                                              \
  dst = *(const bf16x8*)&Bs[(lbuf) * (256 * 64) +                            \
                            (wn * 64 + (j2)*16 + l15) * 64 +                 \
                            ((((ks)*4 + quad) ^ (l15 & 7)) * 8)];

  float4v acc[8][4];
#pragma unroll
  for (int i = 0; i < 8; ++i)
#pragma unroll
    for (int j = 0; j < 4; ++j) acc[i][j] = (float4v){0.f, 0.f, 0.f, 0.f};

  // prologue: tile0 all 4 halves, tile1 A-halves (12 loads/thread total)
  STG(Ab, As, 0, 0, 0);
  STG(Ab, As, 0, 1, 0);
  STG(Bb, Bs, 0, 0, 0);
  STG(Bb, Bs, 0, 1, 0);
  STG(Ab, As, 1, 0, 1);
  STG(Ab, As, 1, 1, 1);
  asm volatile("s_waitcnt vmcnt(4)" ::: "memory");
  __builtin_amdgcn_s_barrier();
  __builtin_amdgcn_sched_barrier(0);

#pragma unroll 1
  for (int t = 0; t < NT; ++t) {
    const int bsel = t & 1;
    bf16x8 af0[4][2], af1[4][2], bf0[2][2], bf1[2][2];

    // ---- P1: quadrant (0,0) --------------------------------------------
#pragma unroll
    for (int i = 0; i < 4; ++i) {
      RD_A(af0[i][0], bsel, i, 0);
      RD_A(af0[i][1], bsel, i, 1);
    }
#pragma unroll
    for (int j = 0; j < 2; ++j) {
      RD_B(bf0[j][0], bsel, j, 0);
      RD_B(bf0[j][1], bsel, j, 1);
    }
    if (t + 1 < NT) STG(Bb, Bs, bsel ^ 1, 0, t + 1);
    __builtin_amdgcn_s_barrier();
    asm volatile("s_waitcnt lgkmcnt(0)" ::: "memory");
    __builtin_amdgcn_sched_barrier(0);
    __builtin_amdgcn_s_setprio(1);
#pragma unroll
    for (int i = 0; i < 4; ++i)
#pragma unroll
      for (int j = 0; j < 2; ++j) {
        acc[i][j] = MFMA16(af0[i][0], bf0[j][0], acc[i][j]);
        acc[i][j] = MFMA16(af0[i][1], bf0[j][1], acc[i][j]);
      }
    __builtin_amdgcn_s_setprio(0);
    __builtin_amdgcn_s_barrier();

    // ---- P2: quadrant (1,0) --------------------------------------------
#pragma unroll
    for (int i = 0; i < 4; ++i) {
      RD_A(af1[i][0], bsel, 4 + i, 0);
      RD_A(af1[i][1], bsel, 4 + i, 1);
    }
    if (t + 1 < NT) STG(Bb, Bs, bsel ^ 1, 1, t + 1);
    __builtin_amdgcn_s_barrier();
    asm volatile("s_waitcnt lgkmcnt(0)" ::: "memory");
    __builtin_amdgcn_sched_barrier(0);
    __builtin_amdgcn_s_setprio(1);
#pragma unroll
    for (int i = 0; i < 4; ++i)
#pragma unroll
      for (int j = 0; j < 2; ++j) {
        acc[4 + i][j] = MFMA16(af1[i][0], bf0[j][0], acc[4 + i][j]);
        acc[4 + i][j] = MFMA16(af1[i][1], bf0[j][1], acc[4 + i][j]);
      }
    __builtin_amdgcn_s_setprio(0);
    __builtin_amdgcn_s_barrier();

    // ---- P3: quadrant (0,1) --------------------------------------------
#pragma unroll
    for (int j = 0; j < 2; ++j) {
      RD_B(bf1[j][0], bsel, 2 + j, 0);
      RD_B(bf1[j][1], bsel, 2 + j, 1);
    }
    if (t + 2 < NT) STG(Ab, As, bsel, 0, t + 2);
    __builtin_amdgcn_s_barrier();
    asm volatile("s_waitcnt lgkmcnt(0)" ::: "memory");
    __builtin_amdgcn_sched_barrier(0);
    __builtin_amdgcn_s_setprio(1);
#pragma unroll
    for (int i = 0; i < 4; ++i)
#pragma unroll
      for (int j = 0; j < 2; ++j) {
        acc[i][2 + j] = MFMA16(af0[i][0], bf1[j][0], acc[i][2 + j]);
        acc[i][2 + j] = MFMA16(af0[i][1], bf1[j][1], acc[i][2 + j]);
      }
    __builtin_amdgcn_s_setprio(0);
    __builtin_amdgcn_s_barrier();

    // ---- P4: quadrant (1,1) --------------------------------------------
    if (t + 2 < NT) STG(Ab, As, bsel, 1, t + 2);
    __builtin_amdgcn_s_barrier();
    __builtin_amdgcn_s_setprio(1);
#pragma unroll
    for (int i = 0; i < 4; ++i)
#pragma unroll
      for (int j = 0; j < 2; ++j) {
        acc[4 + i][2 + j] = MFMA16(af1[i][0], bf1[j][0], acc[4 + i][2 + j]);
        acc[4 + i][2 + j] = MFMA16(af1[i][1], bf1[j][1], acc[4 + i][2 + j]);
      }
    __builtin_amdgcn_s_setprio(0);
    if (t + 2 < NT) {
      asm volatile("s_waitcnt vmcnt(4)" ::: "memory");
    } else if (t + 1 < NT) {
      asm volatile("s_waitcnt vmcnt(0)" ::: "memory");
    }
    __builtin_amdgcn_s_barrier();
    __builtin_amdgcn_sched_barrier(0);
  }
#undef STG
#undef RD_A
#undef RD_B

  const int omb0 = m0 + wm * 128 + quad * 4;
  const int onb0 = nz0 + wn * 64 + l15;
  if (z == 2) {
#pragma unroll
    for (int j = 0; j < 4; ++j) {
      const int n = onb0 + j * 16;
      const float bj = bias[n];
#pragma unroll
      for (int i = 0; i < 8; ++i) {
        const int mrow = omb0 + i * 16;
        const int bb = mrow >> 11, tt = mrow & (Tsz - 1);
        union { bf16 h[4]; uint2 u; } pk;
#pragma unroll
        for (int r = 0; r < 4; ++r) pk.h[r] = (bf16)(acc[i][j][r] + bj);
        *(uint2*)(Vt + ((size_t)(bb * 1024 + n)) * Tsz + tt) = pk.u;
      }
    }
  } else {
    bf16* C = z == 0 ? C0 : C1;
    const float osc = z == 0 ? 0.180336880111124f : 1.0f;  // 0.125*log2(e)
#pragma unroll
    for (int j = 0; j < 4; ++j) {
      const float bj = bias[onb0 + j * 16];
#pragma unroll
      for (int i = 0; i < 8; ++i) {
#pragma unroll
        for (int r = 0; r < 4; ++r) {
          const float v = (acc[i][j][r] + bj) * osc;
          C[(size_t)(omb0 + i * 16 + r) * Csz + onb0 + j * 16] = (bf16)v;
        }
      }
    }
  }
}

// ---------------------------------------------------------------------------
// Output projection: C[M,N] f32 = A[M,K]bf16 @ Bt[N,K]^T + bias.
// 128x64 tile, grid (16,32) = 512 blocks = 2/CU (kept from round 5, ~-14us).
// ---------------------------------------------------------------------------
__global__ __launch_bounds__(256) void gemm_op(
    const bf16* __restrict__ A, const bf16* __restrict__ Bt,
    const float* __restrict__ bias, float* __restrict__ C) {
  __shared__ bf16 As[128 * 32];
  __shared__ bf16 Bs[64 * 32];
  const int tid = threadIdx.x;
  const int wave = tid >> 6, lane = tid & 63;
  const int l15 = lane & 15, quad = lane >> 4;
  const int m0 = blockIdx.y * 128, n0 = blockIdx.x * 64;
  const int wm = (wave >> 1) * 64, wn = (wave & 1) * 32;
  const int srow = tid >> 2, schunk = tid & 3;

  float4v acc[4][2];
#pragma unroll
  for (int i = 0; i < 4; ++i)
#pragma unroll
    for (int j = 0; j < 2; ++j) acc[i][j] = (float4v){0.f, 0.f, 0.f, 0.f};

  for (int k0 = 0; k0 < Csz; k0 += 32) {
    __syncthreads();
#pragma unroll
    for (int p = 0; p < 2; ++p) {
      const int row = p * 64 + srow;
      GLOAD_LDS16(A + (size_t)(m0 + row) * Csz + k0 + schunk * 8,
                  &As[(p * 256 + tid) * 8]);
    }
    GLOAD_LDS16(Bt + (size_t)(n0 + srow) * Csz + k0 + schunk * 8,
                &Bs[tid * 8]);
    __syncthreads();

    bf16x8 af[4], bfr[2];
#pragma unroll
    for (int i = 0; i < 4; ++i)
      af[i] = *(const bf16x8*)&As[(wm + i * 16 + l15) * 32 + quad * 8];
#pragma unroll
    for (int j = 0; j < 2; ++j)
      bfr[j] = *(const bf16x8*)&Bs[(wn + j * 16 + l15) * 32 + quad * 8];
#pragma unroll
    for (int i = 0; i < 4; ++i)
#pragma unroll
      for (int j = 0; j < 2; ++j)
        acc[i][j] = MFMA16(af[i], bfr[j], acc[i][j]);
  }

  const int omb = m0 + wm + quad * 4;
  const int onb = n0 + wn + l15;
#pragma unroll
  for (int j = 0; j < 2; ++j) {
    const float bj = bias[onb + j * 16];
#pragma unroll
    for (int i = 0; i < 4; ++i) {
#pragma unroll
      for (int r = 0; r < 4; ++r)
        C[(size_t)(omb + i * 16 + r) * Csz + onb + j * 16] =
            acc[i][j][r] + bj;
    }
  }
}

// ---------------------------------------------------------------------------
// Flash attention, bf16 MFMA, S^T formulation.
// Round 7: 512 thr = 8 waves x 16 q-rows (block still 128 rows). R4's
// complementary mapping + double-buffered K/V, counted-vmcnt gates.
//   iter s: [stage t+1 -> buf^1] [compute buf] [vmcnt(0)] [barrier]
// ---------------------------------------------------------------------------
__global__ __launch_bounds__(512) void attn_mfma(const bf16* __restrict__ Q,
                                                 const bf16* __restrict__ K,
                                                 const bf16* __restrict__ Vt,
                                                 bf16* __restrict__ Y) {
  __shared__ bf16 Ks[2][64 * 64];
  __shared__ bf16 Vs[2][64 * 64];
  __shared__ bf16 Ps[8][16 * 72];  // per-wave P[q][key], row stride 72

  const int bh = blockIdx.y;
  const int b = bh >> 4, h = bh & 15;
  // sum-balanced complementary mapping (R2/R4, measured best): neighbors
  // (2c,2c+1) -> ranks (c, 15-c); layers y and y+16 complemented.
  int xr = (blockIdx.x & 1) ? (int)(gridDim.x - 1 - (blockIdx.x >> 1))
                            : (int)(blockIdx.x >> 1);
  if (bh >= 16) xr = (int)(gridDim.x - 1) - xr;
  const int i0 = xr * 128;
  const int tid = threadIdx.x;
  const int wave = tid >> 6, lane = tid & 63;  // wave 0..7
  const int l15 = lane & 15, quad = lane >> 4;

  const int srow = tid >> 3;  // 0..63
  const int sch = tid & 7;

  const bf16* kb = K + (size_t)b * Tsz * Csz + h * HDsz;
  const bf16* vb = Vt + (size_t)bh * HDsz * Tsz;

  const int qb = i0 + wave * 16;  // wave's 16 q rows

  bf16x8 qf[2];
  {
    const bf16* qp =
        Q + ((size_t)(b * Tsz + qb + l15)) * Csz + h * HDsz + quad * 8;
    qf[0] = *(const bf16x8*)qp;
    qf[1] = *(const bf16x8*)(qp + 32);
  }

  bf16x8 ones;
#pragma unroll
  for (int j = 0; j < 8; ++j) ones[j] = (bf16)1.0f;

  float4v Of[4];
  float4v accl = (float4v){0.f, 0.f, 0.f, 0.f};
#pragma unroll
  for (int nc = 0; nc < 4; ++nc) Of[nc] = (float4v){0.f, 0.f, 0.f, 0.f};

  const int ntile = i0 / 64 + 2;  // keys 0 .. i0+127 (>= 2 always)

  // stage K/V tile tt into LDS buffer bb: 2 loads/thread (1 K + 1 V)
#define STAGE_KV(tt, bb)                                                     \
  {                                                                          \
    const int c = sch ^ (srow & 7);                                          \
    GLOAD_LDS16(kb + (size_t)((tt)*64 + srow) * Csz + c * 8,                 \
                &Ks[bb][tid * 8]);                                           \
    GLOAD_LDS16(vb + (size_t)srow * Tsz + (tt)*64 + c * 8,                   \
                &Vs[bb][tid * 8]);                                           \
  }

  // prologue: tile 0 resident before first compute
  STAGE_KV(0, 0);
  asm volatile("s_waitcnt vmcnt(0)" ::: "memory");
  __builtin_amdgcn_s_barrier();
  __builtin_amdgcn_sched_barrier(0);

#pragma unroll 1
  for (int t = 0; t < ntile; ++t) {
    const int j0 = t * 64;
    const int buf = t & 1;
    if (t + 1 < ntile) STAGE_KV(t + 1, buf ^ 1);

    if (j0 <= qb + 15) {  // wave-uniform: skip fully-masked tiles
      // ---- S^T = K Q^T : C-layout S^T[key=j0+nc*16+quad*4+r][q=qb+l15]
      float4v S[4];
#pragma unroll
      for (int nc = 0; nc < 4; ++nc) {
        const int row = nc * 16 + l15;
        const bf16x8 k0 =
            *(const bf16x8*)&Ks[buf][row * 64 + ((quad ^ (row & 7)) * 8)];
        const bf16x8 k1 =
            *(const bf16x8*)&Ks[buf][row * 64 + (((quad + 4) ^ (row & 7)) * 8)];
        float4v a = (float4v){0.f, 0.f, 0.f, 0.f};
        a = MFMA16(k0, qf[0], a);
        a = MFMA16(k1, qf[1], a);
        S[nc] = a;
      }

      // ---- causal mask: key > q  (wave-uniform branch, near-diagonal only)
      if (j0 + 63 > qb) {
        const int q = qb + l15;
#pragma unroll
        for (int nc = 0; nc < 4; ++nc) {
          const int keyb = j0 + nc * 16 + quad * 4;
#pragma unroll
          for (int r = 0; r < 4; ++r)
            if (keyb + r > q) S[nc][r] = -1e30f;
        }
      }

      // ---- un-shifted exp2 numerator; P[q][key] -> LDS (b64, r contiguous)
#pragma unroll
      for (int nc = 0; nc < 4; ++nc) {
        bf16x4 pk;
#pragma unroll
        for (int r = 0; r < 4; ++r)
          pk[r] = (bf16)__builtin_amdgcn_exp2f(S[nc][r]);
        *(bf16x4*)&Ps[wave][l15 * 72 + nc * 16 + quad * 4] = pk;
      }

      // ---- P^T B-frags (b128), l, and O^T += V^T P^T (same-wave LDS RAW) --
      bf16x8 pf[2];
#pragma unroll
      for (int kc = 0; kc < 2; ++kc)
        pf[kc] = *(const bf16x8*)&Ps[wave][l15 * 72 + kc * 32 + quad * 8];
      accl = MFMA16(ones, pf[0], accl);
      accl = MFMA16(ones, pf[1], accl);
#pragma unroll
      for (int nc = 0; nc < 4; ++nc) {
        const int row = nc * 16 + l15;
#pragma unroll
        for (int kc = 0; kc < 2; ++kc) {
          const bf16x8 vf = *(const bf16x8*)
              &Vs[buf][row * 64 + (((kc * 4 + quad) ^ (row & 7)) * 8)];
          Of[nc] = MFMA16(vf, pf[kc], Of[nc]);
        }
      }
    }

    // ---- gate: tile t+1 resident before next iter (issued 1 iter ago) ----
    if (t + 1 < ntile) {
      asm volatile("s_waitcnt vmcnt(0)" ::: "memory");
    }
    __builtin_amdgcn_sched_barrier(0);
    __builtin_amdgcn_s_barrier();
    __builtin_amdgcn_sched_barrier(0);
  }
#undef STAGE_KV

  // ---- epilogue: Y[q][h*64+d] = O^T[d][q] / l[q]  (8B stores, r contiguous)
  {
    const float rl = __builtin_amdgcn_rcpf(accl[0]);
    const size_t rowoff = ((size_t)(b * Tsz + qb + l15)) * Csz + h * HDsz;
#pragma unroll
    for (int nc = 0; nc < 4; ++nc) {
      union { bf16 h4[4]; uint2 u; } pk;
#pragma unroll
      for (int r = 0; r < 4; ++r) pk.h4[r] = (bf16)(Of[nc][r] * rl);
      *(uint2*)(Y + rowoff + nc * 16 + quad * 4) = pk.u;
    }
  }
}

extern "C" void kernel_launch(void* const* d_in, const int* in_sizes, int n_in,
                              void* d_out, int out_size, void* d_ws,
                              size_t ws_size, hipStream_t stream) {
  const float* query = (const float*)d_in[0];
  const float* key = (const float*)d_in[1];
  const float* value = (const float*)d_in[2];
  // d_in[3] = att_mask (tril causal) -- hard-coded in attn kernel
  const float* Wq = (const float*)d_in[4];
  const float* bq = (const float*)d_in[5];
  const float* Wk = (const float*)d_in[6];
  const float* bk = (const float*)d_in[7];
  const float* Wv = (const float*)d_in[8];
  const float* bv = (const float*)d_in[9];
  const float* Wp = (const float*)d_in[10];
  const float* bp = (const float*)d_in[11];
  float* out = (float*)d_out;

  char* ws = (char*)d_ws;
  bf16* WT = (bf16*)(ws);
  bf16* vc = (bf16*)(ws + (8u << 20));
  bf16* Qp = (bf16*)(ws + (16u << 20));
  bf16* Kp = (bf16*)(ws + (24u << 20));
  bf16* Vt = (bf16*)(ws + (32u << 20));
  bf16* Yb = vc;
  bf16* qc = (bf16*)d_out;
  bf16* kc = (bf16*)((char*)d_out + (8u << 20));

  const int M = Bsz * Tsz;  // 4096

  // fused cast(q,k,v) + weight transpose: 6144 + 1024 blocks
  prep_bf16<<<dim3(7168), dim3(256), 0, stream>>>(query, key, value, qc, kc,
                                                  vc, Wq, Wk, Wv, Wp, WT);
  // batched QKV projection, 256^2 8-phase; z==0 pre-scales Q; z==2 -> Vt
  gemm256_qkv<<<dim3(Csz / 256, M / 256, 3), dim3(512), 0, stream>>>(
      qc, kc, vc, WT, bq, bk, bv, Qp, Kp, Vt);
  // flash attention (writes bf16 into Yb = old vc slot), 8 waves/block
  attn_mfma<<<dim3(Tsz / 128, Bsz * Hsz), dim3(512), 0, stream>>>(Qp, Kp, Vt,
                                                                  Yb);
  // output projection (f32 into d_out), 128x64 tiles, 512 blocks = 2/CU
  gemm_op<<<dim3(Csz / 64, M / 128), dim3(256), 0, stream>>>(
      Yb, WT + 3u * (Csz * Csz), bp, out);
}